// Round 1
// 355.684 us; speedup vs baseline: 1.0600x; 1.0600x over previous
//
#include <hip/hip_runtime.h>
#include <math.h>

// FutureFutureCrossAttention — MI355X, round 5.
// Shapes: B=8 A=64 K=16 L=30 D=M=128 H=8 hd=16.
// Round-5 changes vs round 4 (attn_kernel rewritten, proj/prep unchanged):
//  - Operand-swapped attention: S^T = K·Q^T via mfma_f32_16x16x16_bf16 (K=16 =
//    head_dim, no zero-padded k-half). Lane then holds P^T[kk][q] with q
//    lane-local: softmax reduce = in-register + 2x shfl_xor(16/32); attn-prob
//    store is a register float4 (pf LDS deleted); PV B-operand layout
//    (k=quad*4+j) EQUALS the C-layout rows => pbuf transpose round-trip deleted
//    (~300 LDS ops/wave removed). ctx epilogue is one float4 store.
//  - LDS trimmed to exactly 32768 B (Kbf 15360 + Vt[16][484] 15488 + bias_ext
//    1920): 5 blocks/CU instead of 4. idx_s/biasm shared arrays replaced by
//    direct (L1-cached) global reads; one __syncthreads removed.
//  - XCD-aware block swizzle (4096%8==0, bijective): 8 consecutive blk (one ba)
//    and one batch b per XCD => gathered K/V working set 1.9 MB fits 4 MB L2.
// Verified fragment layouts (learn_hip m89): 16x16 family, A[m=lane&15][k],
// B[k][n=lane&15], C/D col=lane&15, row=quad*4+reg; k=quad*4+j for K=16.

#define NB 8
#define NA 64
#define NK 16
#define NL 30
#define ND 128
#define NM 128
#define NH 8
#define NHD 16
#define NKK (NK*NL)          // 480
#define FSCALE 0.25f         // 16^-0.5
#define NROWS (NB*NA*NL)     // 15360

typedef __attribute__((ext_vector_type(8))) short bf16x8;
typedef __attribute__((ext_vector_type(4))) short bf16x4;
typedef __attribute__((ext_vector_type(4))) float f32x4;

__device__ __forceinline__ unsigned short bf16r(float x) {
    unsigned u = __float_as_uint(x);
    return (unsigned short)((u + 0x7fffu + ((u >> 16) & 1u)) >> 16);
}
__device__ __forceinline__ float bf16tof(unsigned short h) {
    return __uint_as_float((unsigned)h << 16);
}

// 16x16x16 bf16 MFMA: builtin if present (gfx90a-lineage name), else raw asm
// (v_mfma_f32_16x16x16_bf16 is a valid gfx950 encoding per ISA §10).
__device__ __forceinline__ f32x4 mfma16(bf16x4 a, bf16x4 b, f32x4 c) {
#if __has_builtin(__builtin_amdgcn_mfma_f32_16x16x16bf16_1k)
    return __builtin_amdgcn_mfma_f32_16x16x16bf16_1k(a, b, c, 0, 0, 0);
#else
    f32x4 d;
    asm("v_mfma_f32_16x16x16_bf16 %0, %1, %2, %3"
        : "=&v"(d) : "v"(a), "v"(b), "v"(c));
    return d;
#endif
}

// ---------------------------------------------------------------------------
// prep: blocks 0..7 = (matrix m = bid>>1, k-half = bid&1) transpose W -> bf16
// hi/lo layout Wt[m][n][k]; block 8 = mask-format detect + bias pack.
__global__ __launch_bounds__(256) void prep_kernel(
    const float* __restrict__ Wq, const float* __restrict__ Wk,
    const float* __restrict__ Wv, const float* __restrict__ Wo,
    const float* __restrict__ bq, const float* __restrict__ bk,
    const float* __restrict__ bv, const float* __restrict__ bo,
    const unsigned int* __restrict__ nmask_u, int* __restrict__ mflag,
    short* __restrict__ WtH, short* __restrict__ WtL, float* __restrict__ bias_ws)
{
    const int t = threadIdx.x;
    if (blockIdx.x == 8) {
        __shared__ int not_i32, not_f32;
        if (t == 0) { not_i32 = 0; not_f32 = 0; }
        __syncthreads();
        for (int i = t; i < 2048; i += 256) {
            unsigned u = nmask_u[i];
            if (u > 1u) not_i32 = 1;                       // benign race
            if (u != 0u && u != 0x3F800000u) not_f32 = 1;
        }
        __syncthreads();
        if (t == 0) *mflag = (!not_i32) ? 0 : ((!not_f32) ? 1 : 2);
        if (t < 128) {
            bias_ws[t]       = bq[t];
            bias_ws[128 + t] = bk[t];
            bias_ws[256 + t] = bv[t];
            bias_ws[384 + t] = bo[t];
        }
        return;
    }
    const int m = blockIdx.x >> 1, half = blockIdx.x & 1, d0 = half * 64;
    const float* W = (m == 0) ? Wq : (m == 1) ? Wk : (m == 2) ? Wv : Wo;
    __shared__ __align__(16) float xs[64][132];            // pad 4 -> conflict-free
    for (int i = t; i < 2048; i += 256) {                  // 64x128 f32, float4 loads
        const int dd = i >> 5, j4 = (i & 31) * 4;
        *(float4*)&xs[dd][j4] = *(const float4*)(W + (size_t)(d0 + dd) * NM + j4);
    }
    __syncthreads();
    const int n = t >> 1, hs = t & 1;                      // col n, k-subhalf hs
    unsigned short hb[32], lb[32];
    #pragma unroll
    for (int s = 0; s < 32; ++s) {
        float v = xs[hs*32 + s][n];                        // W[d0+hs*32+s][n]
        unsigned short h = bf16r(v);
        hb[s] = h;
        lb[s] = bf16r(v - bf16tof(h));
    }
    const size_t base = (size_t)m * 16384 + (size_t)n * 128 + d0 + hs * 32;
    #pragma unroll
    for (int g = 0; g < 8; ++g) {
        unsigned long long ph =
              (unsigned long long)hb[4*g]
            | ((unsigned long long)hb[4*g+1] << 16)
            | ((unsigned long long)hb[4*g+2] << 32)
            | ((unsigned long long)hb[4*g+3] << 48);
        unsigned long long pl =
              (unsigned long long)lb[4*g]
            | ((unsigned long long)lb[4*g+1] << 16)
            | ((unsigned long long)lb[4*g+2] << 32)
            | ((unsigned long long)lb[4*g+3] << 48);
        *(unsigned long long*)(WtH + base + g*4) = ph;
        *(unsigned long long*)(WtL + base + g*4) = pl;
    }
}

// ---------------------------------------------------------------------------
// MFMA projection: Y[m] = X @ W[mat_off+m] + b[mat_off+m].
// grid (NROWS/64, nmat); 256 thr = 4 waves; wave w owns rows rt*64+w*16..+15.
// 3-product hi/lo split => ~f32 accuracy. No LDS. NOTE: X/Y may alias (output
// projection runs in place): per-wave, all A loads are issued before any store;
// waves/blocks touch disjoint 16-row groups.
__global__ __launch_bounds__(256, 3) void proj_mfma(
    const float* X,
    const short* __restrict__ WtH, const short* __restrict__ WtL,
    const float* __restrict__ bias_ws,
    float* Y, int mat_off)
{
    const int m    = blockIdx.y;
    const int mi   = mat_off + m;
    const int rt   = blockIdx.x;
    const int t    = threadIdx.x;
    const int lane = t & 63, w = t >> 6;
    const int n    = lane & 15, quad = lane >> 4;

    const short* wh = WtH + (size_t)mi * 16384 + (size_t)n * 128 + quad * 8;
    const short* wl = WtL + (size_t)mi * 16384 + (size_t)n * 128 + quad * 8;

    // A fragments: row = rt*64 + w*16 + n (A[m=lane&15][k=quad*8+j])
    const int arow = rt*64 + w*16 + n;
    const float* xr = X + (size_t)arow * ND + quad*8;
    bf16x8 Ah[4], Al[4];
    #pragma unroll
    for (int ks = 0; ks < 4; ++ks) {
        float4 x0 = *(const float4*)(xr + ks*32);
        float4 x1 = *(const float4*)(xr + ks*32 + 4);
        float xv[8] = {x0.x,x0.y,x0.z,x0.w,x1.x,x1.y,x1.z,x1.w};
        #pragma unroll
        for (int j = 0; j < 8; ++j) {
            unsigned short h = bf16r(xv[j]);
            Ah[ks][j] = (short)h;
            Al[ks][j] = (short)bf16r(xv[j] - bf16tof(h));
        }
    }

    float* yb = Y + (size_t)m * NROWS * NM
                  + (size_t)(rt*64 + w*16 + quad*4) * NM + n;
    #pragma unroll 2
    for (int nt = 0; nt < 8; ++nt) {
        f32x4 acc = {0.f, 0.f, 0.f, 0.f};
        #pragma unroll
        for (int ks = 0; ks < 4; ++ks) {
            bf16x8 bh = *(const bf16x8*)(wh + nt*2048 + ks*32);
            bf16x8 bl = *(const bf16x8*)(wl + nt*2048 + ks*32);
            acc = __builtin_amdgcn_mfma_f32_16x16x32_bf16(Ah[ks], bh, acc, 0, 0, 0);
            acc = __builtin_amdgcn_mfma_f32_16x16x32_bf16(Al[ks], bh, acc, 0, 0, 0);
            acc = __builtin_amdgcn_mfma_f32_16x16x32_bf16(Ah[ks], bl, acc, 0, 0, 0);
        }
        const float bn = bias_ws[mi*128 + nt*16 + n];
        #pragma unroll
        for (int r = 0; r < 4; ++r)
            yb[(size_t)r * NM + nt*16] = acc[r] + bn;
    }
}

// ---------------------------------------------------------------------------
// MFMA attention, operand-swapped (S^T layout). Block = (ba, h) after XCD
// swizzle, 128 threads = 2 waves; wave w owns q rows w*16..w*16+15 (rows 30,31
// padded, stores masked). Lane (n,quad) computes column q = w*16+n:
//   QK: s[tt][r]  = S^T[16tt+4quad+r][q] = K·Q^T + bias   (2x mfma16 hi/lo)
//   softmax: q is lane-local -> in-register + shfl_xor(16,32) across quads
//   attn store: float4 {p0..p3} direct from registers (coalesces across quads)
//   PV: B-frag (k=quad*4+j) == C-layout rows -> no transpose; A = V^T from LDS
//   ctx: D[d=quad*4+r][q=n] -> one float4 store.
__global__ __launch_bounds__(128, 2) void attn_kernel(
    const float* __restrict__ qp, const float* __restrict__ kp, const float* __restrict__ vp,
    const float* __restrict__ geom_bias, const int* __restrict__ nidx,
    const void* __restrict__ nmask, const int* __restrict__ mask_fmt,
    float* __restrict__ attn_out, float* __restrict__ ctx_out)
{
    __shared__ __align__(16) short Kbf[NKK][16];   // gathered K bf16 [kk][hd]  15360 B
    __shared__ __align__(16) short Vt[16][484];    // gathered V^T bf16 [hd][kk] 15488 B
    __shared__ __align__(16) float bias_ext[NKK];  //                            1920 B
    // total = 32768 B exactly -> 5 blocks/CU

    const int t    = threadIdx.x;
    const int bid  = blockIdx.x;
    // XCD swizzle: 4096 blocks, 8 XCDs, bijective since 4096 % 8 == 0.
    const int blk  = (bid & 7) * ((NB*NA*NH) >> 3) + (bid >> 3);
    const int h    = blk & 7;
    const int ba   = blk >> 3;
    const int b    = ba >> 6;             // A = 64
    const int lane = t & 63;
    const int w    = t >> 6;              // wave id = q-tile id
    const int n    = lane & 15;
    const int quad = lane >> 4;

    // ---- stage gathered K (bf16) and V^T (bf16) ----
    for (int i = t; i < NKK*4; i += 128) {
        const int kk = i >> 2, p = i & 3;
        const int kn = kk / NL, l = kk - kn*NL;
        const int nb = nidx[ba*NK + kn];                   // L1-cached scalar
        const size_t off = ((size_t)(b*NA + nb)*NL + l)*NM + h*NHD + p*4;
        float4 kv = *(const float4*)(kp + off);
        unsigned long long pk =
              (unsigned long long)bf16r(kv.x)
            | ((unsigned long long)bf16r(kv.y) << 16)
            | ((unsigned long long)bf16r(kv.z) << 32)
            | ((unsigned long long)bf16r(kv.w) << 48);
        *(unsigned long long*)&Kbf[kk][p*4] = pk;
        float4 vv = *(const float4*)(vp + off);
        Vt[p*4+0][kk] = (short)bf16r(vv.x);
        Vt[p*4+1][kk] = (short)bf16r(vv.y);
        Vt[p*4+2][kk] = (short)bf16r(vv.z);
        Vt[p*4+3][kk] = (short)bf16r(vv.w);
    }
    {
        const int fmt = *mask_fmt;
        for (int i = t; i < NKK; i += 128) {
            const int kn = i / NL;
            bool mv;
            if (fmt == 0)      mv = ((const int*)nmask)[ba*NK + kn] != 0;
            else if (fmt == 1) mv = ((const float*)nmask)[ba*NK + kn] != 0.0f;
            else               mv = ((const unsigned char*)nmask)[ba*NK + kn] != 0;
            bias_ext[i] = mv ? geom_bias[ba*NK + kn] : -INFINITY;
        }
    }

    // ---- Q B-fragment: lane holds Q[q=w*16+n][d=quad*4+j], hi/lo, SCALE folded
    bf16x4 q_hi = {0,0,0,0}, q_lo = {0,0,0,0};
    const int qrow = w*16 + n;
    if (qrow < NL) {
        const float* qb = qp + ((size_t)ba*NL + qrow)*NM + h*NHD + quad*4;
        float4 x = *(const float4*)qb;
        float xv[4] = {x.x, x.y, x.z, x.w};
        #pragma unroll
        for (int j = 0; j < 4; ++j) {
            float xs = xv[j] * FSCALE;
            unsigned short hv = bf16r(xs);
            q_hi[j] = (short)hv;
            q_lo[j] = (short)bf16r(xs - bf16tof(hv));
        }
    }
    __syncthreads();   // Kbf / Vt / bias_ext ready

    // ---- S^T = K·Q^T: 30 tiles; lane gets rows kk=16tt+4quad+r, col q=n ----
    float s[NL][4];
    #pragma unroll
    for (int tt = 0; tt < NL; ++tt) {
        bf16x4 kf = *(const bf16x4*)&Kbf[tt*16 + n][quad*4];   // A[m=kk][k=d]
        f32x4 acc = {0.f, 0.f, 0.f, 0.f};
        acc = mfma16(kf, q_hi, acc);
        acc = mfma16(kf, q_lo, acc);
        const f32x4 bv = *(const f32x4*)&bias_ext[tt*16 + quad*4]; // broadcast read
        #pragma unroll
        for (int r = 0; r < 4; ++r) s[tt][r] = acc[r] + bv[r];
    }

    // ---- softmax along kk (q lane-local; reduce across quads only) ----
    float mx = -INFINITY;
    #pragma unroll
    for (int tt = 0; tt < NL; ++tt)
        #pragma unroll
        for (int r = 0; r < 4; ++r) mx = fmaxf(mx, s[tt][r]);
    mx = fmaxf(mx, __shfl_xor(mx, 16));
    mx = fmaxf(mx, __shfl_xor(mx, 32));
    const bool okr = (mx > -INFINITY);      // false only if all kk masked
    float sum = 0.f;
    #pragma unroll
    for (int tt = 0; tt < NL; ++tt) {
        #pragma unroll
        for (int r = 0; r < 4; ++r) {
            float p = okr ? __expf(s[tt][r] - mx) : 0.f;
            s[tt][r] = p;
            sum += p;
        }
    }
    sum += __shfl_xor(sum, 16);
    sum += __shfl_xor(sum, 32);
    const float inv = (sum > 0.f) ? 1.f / sum : 0.f;

    // ---- PV + register-direct attn store ----
    float* arow = attn_out + (size_t)blk * NL * NKK + (size_t)qrow * NKK;
    f32x4 ctx = {0.f, 0.f, 0.f, 0.f};
    #pragma unroll
    for (int tt = 0; tt < NL; ++tt) {
        const float p0 = s[tt][0]*inv, p1 = s[tt][1]*inv;
        const float p2 = s[tt][2]*inv, p3 = s[tt][3]*inv;
        if (qrow < NL) {
            float4 o = {p0, p1, p2, p3};
            *(float4*)(arow + tt*16 + quad*4) = o;         // quads tile the row
        }
        bf16x4 pb;
        pb[0] = (short)bf16r(p0); pb[1] = (short)bf16r(p1);
        pb[2] = (short)bf16r(p2); pb[3] = (short)bf16r(p3); // B[k=quad*4+j][q=n]
        bf16x4 vf = *(const bf16x4*)&Vt[n][tt*16 + quad*4]; // A[m=d=n][k=kk]
        ctx = mfma16(vf, pb, ctx);
    }
    // ctx: D[d=quad*4+r][q=n] -> contiguous d => float4
    if (qrow < NL) {
        float4 c = {ctx[0], ctx[1], ctx[2], ctx[3]};
        *(float4*)(ctx_out + ((size_t)ba*NL + qrow)*NM + h*NHD + quad*4) = c;
    }
}

// ---------------------------------------------------------------------------
extern "C" void kernel_launch(void* const* d_in, const int* in_sizes, int n_in,
                              void* d_out, int out_size, void* d_ws, size_t ws_size,
                              hipStream_t stream)
{
    const float* x    = (const float*)d_in[0];
    const float* gb   = (const float*)d_in[1];
    const float* Wq   = (const float*)d_in[2];
    const float* bq   = (const float*)d_in[3];
    const float* Wk   = (const float*)d_in[4];
    const float* bk   = (const float*)d_in[5];
    const float* Wv   = (const float*)d_in[6];
    const float* bv   = (const float*)d_in[7];
    const float* Wo   = (const float*)d_in[8];
    const float* bo   = (const float*)d_in[9];
    const int*   nidx = (const int*)d_in[10];
    const void*  nmask= d_in[11];

    float* out  = (float*)d_out;                       // [15360, 128]
    float* attn = out + (size_t)NROWS * NM;            // [B,A,H,L,K,L] flat

    float* qp = (float*)d_ws;                          // 3 x 7.86 MB (contiguous)
    float* kp = qp + (size_t)NROWS * NM;
    float* vp = kp + (size_t)NROWS * NM;
    int*   mflag   = (int*)(vp + (size_t)NROWS * NM);
    float* bias_ws = (float*)(mflag + 4);              // [4][128]
    short* WtH     = (short*)(bias_ws + 512);          // [4][128][128] bf16 hi
    short* WtL     = WtH + 4 * 16384;                  // [4][128][128] bf16 lo

    prep_kernel<<<9, 256, 0, stream>>>(Wq, Wk, Wv, Wo, bq, bk, bv, bo,
                                       (const unsigned int*)nmask, mflag,
                                       WtH, WtL, bias_ws);
    dim3 gproj(NROWS/64, 3);
    proj_mfma<<<gproj, 256, 0, stream>>>(x, WtH, WtL, bias_ws, qp, 0);
    attn_kernel<<<NB*NA*NH, 128, 0, stream>>>(qp, kp, vp, gb, nidx, nmask, mflag,
                                              attn, /*ctx aliases out*/ out);
    dim3 gout(NROWS/64, 1);
    proj_mfma<<<gout, 256, 0, stream>>>(out, WtH, WtL, bias_ws, out, 3);
}